// Round 3
// baseline (1106.532 us; speedup 1.0000x reference)
//
#include <hip/hip_runtime.h>
#include <hip/hip_bf16.h>

constexpr int BN = 8, HH = 512, WW = 512;
constexpr int PIX = HH * WW;
constexpr float EPSF = 1e-4f;

__device__ __forceinline__ float b2f(__hip_bfloat16 x) { return __bfloat162float(x); }
__device__ __forceinline__ __hip_bfloat16 f2b(float x) { return __float2bfloat16(x); }
__device__ __forceinline__ unsigned int bfbits(float x) {
    union { __hip_bfloat16 b; unsigned short u; } cv; cv.b = f2b(x); return (unsigned int)cv.u;
}

// ---- workspace float offsets (small region) ----
constexpr int OFF_TOT = 0;       // 8*16 per-image channel totals  (atomics, zeroed)
constexpr int OFF_ROW0 = 128;    // row 0 sums
constexpr int OFF_ROW1 = 256;    // row 511 sums
constexpr int OFF_COL0 = 384;    // col 0 sums
constexpr int OFF_COL1 = 512;    // col 511 sums
constexpr int OFF_COR = 640;     // corners [b][hi][wi][16]  (plain stores)
constexpr int OFF_WR  = 2048;    // w2 reordered [tap][ic][oc], 2304 floats
constexpr int OFF_EH  = 4608;    // 8*37
constexpr int OFF_CH  = 5120;    // 8*37
// ---- big buffers (byte offsets) ----
constexpr size_t OFF_H1B = 65536;                        // h1 NHWC bf16
constexpr size_t H1_BYTES = (size_t)BN * PIX * 16 * 2;   // 67,108,864
constexpr size_t OFF_XGB = OFF_H1B + H1_BYTES;           // xg fp32 (3 planes per image)
constexpr size_t XG_BYTES = (size_t)BN * 3 * PIX * 4;    // 25,165,824
constexpr size_t OFF_TPB = OFF_XGB + XG_BYTES;           // tpl fp32 (4 planes)
constexpr size_t TP_BYTES = (size_t)4 * BN * PIX * 4;    // 33,554,432
constexpr size_t WS_NEEDED = OFF_TPB + TP_BYTES;         // 125,894,656  (fits: 134.3 MB proven)

// ---------------- prep: zero atomic slots, reorder w2 -> [tap][ic][oc] ----------------
__global__ void prep_kernel(const float* __restrict__ w2, float* __restrict__ wsf) {
    int t = threadIdx.x;
    for (int i = t; i < 640; i += 256) wsf[i] = 0.f;
    for (int i = t; i < 2304; i += 256) {
        int tap = i % 9, ic = (i / 9) % 16, oc = i / 144;
        wsf[OFF_WR + tap * 256 + ic * 16 + oc] = w2[i];
    }
}

// ---------------- conv1: batch(fp32 NCHW) -> h1(bf16 NHWC), silu ----------------
__global__ __launch_bounds__(256) void conv1_kernel(const float* __restrict__ batch,
                                                    const float* __restrict__ w1,
                                                    const float* __restrict__ b1,
                                                    __hip_bfloat16* __restrict__ h1) {
    int w = blockIdx.x * 64 + threadIdx.x;
    int h = blockIdx.y * 4 + threadIdx.y;
    int b = blockIdx.z;
    float v[27];
#pragma unroll
    for (int ic = 0; ic < 3; ic++) {
        const float* p = batch + (size_t)(b * 3 + ic) * PIX;
#pragma unroll
        for (int kh = 0; kh < 3; kh++) {
            int hh = h + kh - 1;
#pragma unroll
            for (int kw = 0; kw < 3; kw++) {
                int ww = w + kw - 1;
                float x = 0.f;
                if (hh >= 0 && hh < HH && ww >= 0 && ww < WW) x = p[hh * WW + ww];
                v[ic * 9 + kh * 3 + kw] = x;
            }
        }
    }
    float o[16];
#pragma unroll
    for (int oc = 0; oc < 16; oc++) {
        float a = b1[oc];
#pragma unroll
        for (int j = 0; j < 27; j++) a += v[j] * w1[oc * 27 + j];  // consecutive -> s_load batches
        o[oc] = a / (1.f + __expf(-a));
    }
    unsigned int u[8];
#pragma unroll
    for (int i = 0; i < 8; i++) u[i] = bfbits(o[2 * i]) | (bfbits(o[2 * i + 1]) << 16);
    uint4* dst = (uint4*)(h1 + (((size_t)(b * HH) + h) * WW + w) * 16);
    dst[0] = make_uint4(u[0], u[1], u[2], u[3]);
    dst[1] = make_uint4(u[4], u[5], u[6], u[7]);
}

// ---------------- conv2 fused with conv3-mean reduction ----------------
// Computes h2 = silu(conv2(h1)) in registers only; accumulates per-image, per-channel:
// total, row0/row511 sums, col0/col511 sums, 4 corner values. No h2 store.
__global__ __launch_bounds__(256) void conv2_kernel(const __hip_bfloat16* __restrict__ h1,
                                                    const float* __restrict__ wr,
                                                    const float* __restrict__ b2,
                                                    float* __restrict__ wsf) {
    int tx = threadIdx.x, ty = threadIdx.y;
    int w = blockIdx.x * 64 + tx;
    int h = blockIdx.y * 4 + ty;
    int b = blockIdx.z;
    float acc[16];
#pragma unroll
    for (int oc = 0; oc < 16; oc++) acc[oc] = b2[oc];
#pragma unroll
    for (int kh = 0; kh < 3; kh++) {
        int hh = h + kh - 1;
#pragma unroll
        for (int kw = 0; kw < 3; kw++) {
            int ww = w + kw - 1;
            int tap = kh * 3 + kw;
            float v[16];
            bool ok = (hh >= 0) && (hh < HH) && (ww >= 0) && (ww < WW);
            if (ok) {
                const uint4* p = (const uint4*)(h1 + (((size_t)(b * HH) + hh) * WW + ww) * 16);
                uint4 u0 = p[0], u1 = p[1];
                unsigned int uu[8] = {u0.x, u0.y, u0.z, u0.w, u1.x, u1.y, u1.z, u1.w};
#pragma unroll
                for (int i = 0; i < 8; i++) {
                    v[2 * i]     = __uint_as_float(uu[i] << 16);
                    v[2 * i + 1] = __uint_as_float(uu[i] & 0xffff0000u);
                }
            } else {
#pragma unroll
                for (int i = 0; i < 16; i++) v[i] = 0.f;
            }
            const float* Wt = wr + tap * 256;   // [ic][oc] consecutive -> s_load_dwordx16
#pragma unroll
            for (int ic = 0; ic < 16; ic++) {
#pragma unroll
                for (int oc = 0; oc < 16; oc++) acc[oc] += v[ic] * Wt[ic * 16 + oc];
            }
        }
    }
    float s[16];
#pragma unroll
    for (int oc = 0; oc < 16; oc++) {
        float a = acc[oc];
        s[oc] = a / (1.f + __expf(-a));
    }
    // per-wave (one wave = one row segment of 64 cols) reductions
    float rw[16];
#pragma unroll
    for (int c = 0; c < 16; c++) {
        float r = s[c];
#pragma unroll
        for (int d = 1; d < 64; d <<= 1) r += __shfl_xor(r, d, 64);
        rw[c] = r;
    }
    __shared__ float part[4][16];
    if (tx == 0) {
#pragma unroll
        for (int c = 0; c < 16; c++) part[ty][c] = rw[c];
    }
    __syncthreads();
    int tid = ty * 64 + tx;
    if (tid < 16) {
        float t4 = part[0][tid] + part[1][tid] + part[2][tid] + part[3][tid];
        atomicAdd(&wsf[OFF_TOT + b * 16 + tid], t4);
    }
    if (h == 0 && tx == 0)
        for (int c = 0; c < 16; c++) atomicAdd(&wsf[OFF_ROW0 + b * 16 + c], rw[c]);
    if (h == HH - 1 && tx == 0)
        for (int c = 0; c < 16; c++) atomicAdd(&wsf[OFF_ROW1 + b * 16 + c], rw[c]);
    if (w == 0)
        for (int c = 0; c < 16; c++) atomicAdd(&wsf[OFF_COL0 + b * 16 + c], s[c]);
    if (w == WW - 1)
        for (int c = 0; c < 16; c++) atomicAdd(&wsf[OFF_COL1 + b * 16 + c], s[c]);
    if ((h == 0 || h == HH - 1) && (w == 0 || w == WW - 1)) {
        int hi = (h == 0) ? 0 : 1, wi = (w == 0) ? 0 : 1;
        for (int c = 0; c < 16; c++) wsf[OFF_COR + ((b * 2 + hi) * 2 + wi) * 16 + c] = s[c];
    }
}

// ---------------- filter: assemble mean via T(ic,kh,kw), build separable taps ----------------
__global__ void filter_kernel(const float* __restrict__ w3, const float* __restrict__ b3,
                              float* __restrict__ wsf) {
    int b = blockIdx.x, t = threadIdx.x;   // 160 threads
    __shared__ float red[160];
    float val = 0.f;
    if (t < 144) {
        int ic = t / 9, tap = t % 9, kh = tap / 3, kw = tap % 3;
        float T = wsf[OFF_TOT + b * 16 + ic];
        int hi = -1, wi = -1;
        if (kh == 0) { T -= wsf[OFF_ROW1 + b * 16 + ic]; hi = 1; }
        else if (kh == 2) { T -= wsf[OFF_ROW0 + b * 16 + ic]; hi = 0; }
        if (kw == 0) { T -= wsf[OFF_COL1 + b * 16 + ic]; wi = 1; }
        else if (kw == 2) { T -= wsf[OFF_COL0 + b * 16 + ic]; wi = 0; }
        if (hi >= 0 && wi >= 0) T += wsf[OFF_COR + ((b * 2 + hi) * 2 + wi) * 16 + ic];
        val = w3[t] * T;                    // w3 flat index = ic*9 + kh*3 + kw = t
    }
    red[t] = val;
    __syncthreads();
    __shared__ float sh_mean;
    if (t == 0) {
        float S = 0.f;
        for (int i = 0; i < 144; i++) S += red[i];
        sh_mean = b3[0] + S * (1.f / (float)PIX);
    }
    __syncthreads();
    float scale = fminf(2.5f, fmaxf(-2.5f, sh_mean));
    float sd = exp2f(scale);
    float fs = ceilf(3.f * sd + 0.5f);
    float e = 0.f, c = 0.f;
    if (t < 37) {
        float x = (float)(t - 18);
        if (fabsf(x) <= fs) {
            float q = x / sd;
            e = __expf(-0.5f * q * q);
            c = -x / (sd * sd * sd * 6.28318530717958647692f) * e;
        }
    }
    __shared__ float sa[40], sb[40];
    if (t < 37) { sa[t] = e; sb[t] = fabsf(c); }
    __syncthreads();
    __shared__ float Se, Sc;
    if (t == 0) {
        float a = 0.f, d = 0.f;
        for (int i = 0; i < 37; i++) { a += sa[i]; d += sb[i]; }
        Se = a; Sc = d;
    }
    __syncthreads();
    if (t < 37) {
        wsf[OFF_EH + b * 37 + t] = e / Se;
        wsf[OFF_CH + b * 37 + t] = c / Sc;
    }
}

// ---------------- xg = gcm*batch + RGB_order -> out ch2..4 (4 px/thread) ----------------
__global__ __launch_bounds__(256) void xgrgb_kernel(const float* __restrict__ batch,
                                                    const float* __restrict__ gcm,
                                                    float* __restrict__ xg,
                                                    float* __restrict__ out) {
    int w4 = (blockIdx.x * 64 + threadIdx.x) * 4;
    int h = blockIdx.y * 4 + threadIdx.y;
    int b = blockIdx.z;
    size_t p = (size_t)h * WW + w4;
    float4 v0 = *(const float4*)(batch + (size_t)(b * 3 + 0) * PIX + p);
    float4 v1 = *(const float4*)(batch + (size_t)(b * 3 + 1) * PIX + p);
    float4 v2 = *(const float4*)(batch + (size_t)(b * 3 + 2) * PIX + p);
    float g[9];
#pragma unroll
    for (int i = 0; i < 9; i++) g[i] = gcm[i];
#pragma unroll
    for (int i = 0; i < 3; i++) {
        float4 o;
        o.x = g[i*3] * v0.x + g[i*3+1] * v1.x + g[i*3+2] * v2.x;
        o.y = g[i*3] * v0.y + g[i*3+1] * v1.y + g[i*3+2] * v2.y;
        o.z = g[i*3] * v0.z + g[i*3+1] * v1.z + g[i*3+2] * v2.z;
        o.w = g[i*3] * v0.w + g[i*3+1] * v1.w + g[i*3+2] * v2.w;
        *(float4*)(xg + (size_t)(b * 3 + i) * PIX + p) = o;
    }
    float a0[4] = {v0.x, v0.y, v0.z, v0.w};
    float a1[4] = {v1.x, v1.y, v1.z, v1.w};
    float a2[4] = {v2.x, v2.y, v2.z, v2.w};
    float r[3][4];
#pragma unroll
    for (int j = 0; j < 4; j++) {
        float x0 = a0[j], x1 = a1[j], x2 = a2[j];
        int mx  = (x0 >= x1 && x0 >= x2) ? 0 : ((x1 >= x2) ? 1 : 2);
        int mx2 = (x2 >= x1 && x2 >= x0) ? 2 : ((x1 >= x0) ? 1 : 0);
        int mn  = (x0 <= x1 && x0 <= x2) ? 0 : ((x1 <= x2) ? 1 : 2);
        int mn2 = (x2 <= x1 && x2 <= x0) ? 2 : ((x1 <= x0) ? 1 : 0);
#pragma unroll
        for (int c = 0; c < 3; c++)
            r[c][j] = 0.5f * ((float)(c == mx) + (float)(c == mx2))
                    - 0.5f * ((float)(c == mn) + (float)(c == mn2));
    }
#pragma unroll
    for (int c = 0; c < 3; c++) {
        float4 o = {r[c][0], r[c][1], r[c][2], r[c][3]};
        *(float4*)(out + (size_t)(b * 6 + 2 + c) * PIX + p) = o;
    }
}

// ---------------- horizontal separable pass: xg -> t0..t3 ----------------
__global__ __launch_bounds__(256) void horiz_kernel(const float* __restrict__ xg,
                                                    const float* __restrict__ ehat,
                                                    const float* __restrict__ chat,
                                                    float* __restrict__ t) {
    __shared__ float L[3][296];
    int tid = threadIdx.x;
    int w0 = blockIdx.x * 256;
    int h = blockIdx.y;
    int b = blockIdx.z;
    for (int i = tid; i < 3 * 292; i += 256) {
        int c = i / 292, j = i - c * 292;
        int gw = w0 - 18 + j;
        float x = 0.f;
        if (gw >= 0 && gw < WW) x = xg[(size_t)(b * 3 + c) * PIX + h * WW + gw];
        L[c][j] = x;
    }
    __syncthreads();
    const float* eh = ehat + b * 37; const float* ch = chat + b * 37;
    float s0e = 0.f, s0c = 0.f, s1e = 0.f, s2e = 0.f;
    for (int k = 0; k < 37; k++) {
        float ce = eh[k], cc = ch[k];
        float a0 = L[0][tid + k], a1 = L[1][tid + k], a2 = L[2][tid + k];
        s0e += ce * a0; s0c += cc * a0; s1e += ce * a1; s2e += ce * a2;
    }
    int w = w0 + tid;
    size_t p = (size_t)b * PIX + h * WW + w;
    const size_t PL = (size_t)BN * PIX;
    t[0 * PL + p] = s0e;
    t[1 * PL + p] = s1e;
    t[2 * PL + p] = s2e;
    t[3 * PL + p] = s0c;
}

// ---------------- vertical pass + final math -> out ch0,1,5 (4 rows/thread) ----------------
__global__ __launch_bounds__(256) void vert_kernel(const float* __restrict__ t,
                                                   const float* __restrict__ ehat,
                                                   const float* __restrict__ chat,
                                                   float* __restrict__ out) {
    int tx = threadIdx.x, ty = threadIdx.y;
    int w = blockIdx.x * 64 + tx;
    int b = blockIdx.z;
    int h0 = (blockIdx.y * 4 + ty) * 4;
    const float* eh = ehat + b * 37; const float* ch = chat + b * 37;
    const size_t PL = (size_t)BN * PIX;
    const float* t0 = t + 0 * PL + (size_t)b * PIX;
    const float* t1 = t + 1 * PL + (size_t)b * PIX;
    const float* t2 = t + 2 * PL + (size_t)b * PIX;
    const float* t3 = t + 3 * PL + (size_t)b * PIX;
    float E[4] = {0,0,0,0}, Ex[4] = {0,0,0,0}, Ey[4] = {0,0,0,0};
    float El[4] = {0,0,0,0}, Ell[4] = {0,0,0,0};
    for (int jj = 0; jj < 40; jj++) {
        int j = h0 - 18 + jj;
        if (j < 0 || j >= HH) continue;
        int idx = j * WW + w;
        float a0 = t0[idx], a1 = t1[idx], a2 = t2[idx], a3 = t3[idx];
#pragma unroll
        for (int i = 0; i < 4; i++) {
            int k = jj - i;
            if (k >= 0 && k < 37) {
                float ce = eh[k], cc = ch[k];
                E[i] += ce * a0; Ex[i] += cc * a0; Ey[i] += ce * a3;
                El[i] += ce * a1; Ell[i] += ce * a2;
            }
        }
    }
#pragma unroll
    for (int i = 0; i < 4; i++) {
        int h = h0 + i;
        float Hf = atanf(El[i] / (Ell[i] + EPSF));
        float S = logf((El[i] * El[i] + Ell[i] * Ell[i]) / (E[i] * E[i] + EPSF) + EPSF);
        float rx = Ex[i] / (E[i] + EPSF), ry = Ey[i] / (E[i] + EPSF);
        float Wv = atanf(rx * rx + ry * ry);
        size_t base = (size_t)(b * 6) * PIX + h * WW + w;
        out[base] = Hf;
        out[base + PIX] = S;
        out[base + 5 * (size_t)PIX] = Wv;
    }
}

extern "C" void kernel_launch(void* const* d_in, const int* in_sizes, int n_in,
                              void* d_out, int out_size, void* d_ws, size_t ws_size,
                              hipStream_t stream) {
    const float* batch = (const float*)d_in[0];
    const float* gcm   = (const float*)d_in[1];
    const float* w1    = (const float*)d_in[2];
    const float* b1    = (const float*)d_in[3];
    const float* w2    = (const float*)d_in[4];
    const float* b2    = (const float*)d_in[5];
    const float* w3    = (const float*)d_in[6];
    const float* b3    = (const float*)d_in[7];
    float* out = (float*)d_out;

    if (ws_size < WS_NEEDED) return;

    float* wsf = (float*)d_ws;
    __hip_bfloat16* h1 = (__hip_bfloat16*)((char*)d_ws + OFF_H1B);
    float* xg  = (float*)((char*)d_ws + OFF_XGB);
    float* tpl = (float*)((char*)d_ws + OFF_TPB);
    float* ehat = wsf + OFF_EH;
    float* chat = wsf + OFF_CH;

    prep_kernel<<<dim3(1), dim3(256), 0, stream>>>(w2, wsf);

    dim3 blk(64, 4), grd(WW / 64, HH / 4, BN);
    conv1_kernel<<<grd, blk, 0, stream>>>(batch, w1, b1, h1);
    conv2_kernel<<<grd, blk, 0, stream>>>(h1, wsf + OFF_WR, b2, wsf);
    filter_kernel<<<dim3(8), dim3(160), 0, stream>>>(w3, b3, wsf);
    xgrgb_kernel<<<dim3(2, 128, 8), blk, 0, stream>>>(batch, gcm, xg, out);
    horiz_kernel<<<dim3(WW / 256, HH, BN), dim3(256), 0, stream>>>(xg, ehat, chat, tpl);
    vert_kernel<<<dim3(8, 32, 8), blk, 0, stream>>>(tpl, ehat, chat, out);
}

// Round 5
// 311.156 us; speedup vs baseline: 3.5562x; 3.5562x over previous
//
#include <hip/hip_runtime.h>
#include <hip/hip_bf16.h>

constexpr int BN = 8, HH = 512, WW = 512;
constexpr int PIX = HH * WW;
constexpr float EPSF = 1e-4f;
constexpr int HP = 514;                       // padded dim
constexpr size_t SZP = (size_t)HP * HP * 8;   // elements per half-channel plane (8 ch bf16)

__device__ __forceinline__ float b2f(__hip_bfloat16 x) { return __bfloat162float(x); }
__device__ __forceinline__ __hip_bfloat16 f2b(float x) { return __float2bfloat16(x); }
__device__ __forceinline__ unsigned short bfbits(float x) {
    union { __hip_bfloat16 b; unsigned short u; } cv; cv.b = f2b(x); return cv.u;
}

typedef __attribute__((ext_vector_type(8))) short bf16x8;   // MFMA A/B frag (4 VGPRs)
typedef __attribute__((ext_vector_type(4))) float f32x4;    // MFMA C/D frag

// ---- workspace float offsets (small region) ----
constexpr int OFF_TOT = 0;       // 8*16 per-image channel totals (atomics)
constexpr int OFF_ROW0 = 128;
constexpr int OFF_ROW1 = 256;
constexpr int OFF_COL0 = 384;
constexpr int OFF_COL1 = 512;
constexpr int OFF_COR = 640;     // corners [b][hi][wi][16]
constexpr int OFF_WR  = 2048;    // A-fragment weights hi(2560 bf16) + lo(2560 bf16) = 2560 floats
constexpr int OFF_EH  = 4608;    // 8*37
constexpr int OFF_CH  = 5120;    // 8*37
// ---- big buffers (byte offsets) ----
constexpr size_t OFF_H1B = 65536;                          // h1 padded, 2 half-planes/img
constexpr size_t H1_BYTES = (size_t)BN * 2 * SZP * 2;      // 67,634,176
constexpr size_t OFF_XGB = OFF_H1B + H1_BYTES;             // xg fp32
constexpr size_t XG_BYTES = (size_t)BN * 3 * PIX * 4;      // 25,165,824
constexpr size_t OFF_TPB = OFF_XGB + XG_BYTES;             // tpl fp32 (4 planes)
constexpr size_t TP_BYTES = (size_t)4 * BN * PIX * 4;      // 33,554,432
constexpr size_t WS_NEEDED = OFF_TPB + TP_BYTES;           // ~126.4 MB (134.3 proven)

// ---------------- prep: zero atomic slots, swizzle w2 into hi/lo A-fragments ----------------
// A[m=oc][k], k = ks*32 + q*8 + j ; tap = kg>>4, ic = kg&15 (kg = global K index)
// hi = rn-bf16(w), lo = rn-bf16(w - hi): two-term split recovers ~fp32 weight precision.
__global__ void prep_kernel(const float* __restrict__ w2, float* __restrict__ wsf) {
    int t = threadIdx.x;
    for (int i = t; i < 640; i += 256) wsf[i] = 0.f;
    unsigned short* ab = (unsigned short*)(wsf + OFF_WR);
    for (int idx = t; idx < 5120; idx += 256) {
        int part = idx / 2560;               // 0 = hi, 1 = lo
        int id = idx - part * 2560;
        int ks = id >> 9, rem = id & 511, lane = rem >> 3, j = id & 7;
        int oc = lane & 15, q = lane >> 4;
        int k = q * 8 + j;
        int tap = 2 * ks + (k >> 4), ic = k & 15;
        float val = (tap <= 8) ? w2[oc * 144 + ic * 9 + tap] : 0.f;
        float hv = b2f(f2b(val));
        ab[idx] = (part == 0) ? bfbits(val) : bfbits(val - hv);
    }
}

// ---------------- zero the 1-px border of each half-plane ----------------
__global__ void border_kernel(__hip_bfloat16* __restrict__ h1p) {
    int p = blockIdx.x;                       // 0..15 plane-img
    for (int i = threadIdx.x; i < 2052; i += 256) {
        int hp, wp;
        if (i < 514) { hp = 0; wp = i; }
        else if (i < 1028) { hp = 513; wp = i - 514; }
        else if (i < 1540) { hp = i - 1028 + 1; wp = 0; }
        else { hp = i - 1540 + 1; wp = 513; }
        *(uint4*)(h1p + (size_t)p * SZP + ((size_t)hp * HP + wp) * 8) = make_uint4(0, 0, 0, 0);
    }
}

// ---------------- conv1: batch(fp32 NCHW) -> h1p (padded, 2 half-planes), silu ----------------
__global__ __launch_bounds__(256) void conv1_kernel(const float* __restrict__ batch,
                                                    const float* __restrict__ w1,
                                                    const float* __restrict__ b1,
                                                    __hip_bfloat16* __restrict__ h1p) {
    int w = blockIdx.x * 64 + threadIdx.x;
    int h = blockIdx.y * 4 + threadIdx.y;
    int b = blockIdx.z;
    float v[27];
#pragma unroll
    for (int ic = 0; ic < 3; ic++) {
        const float* p = batch + (size_t)(b * 3 + ic) * PIX;
#pragma unroll
        for (int kh = 0; kh < 3; kh++) {
            int hh = h + kh - 1;
#pragma unroll
            for (int kw = 0; kw < 3; kw++) {
                int ww = w + kw - 1;
                float x = 0.f;
                if (hh >= 0 && hh < HH && ww >= 0 && ww < WW) x = p[hh * WW + ww];
                v[ic * 9 + kh * 3 + kw] = x;
            }
        }
    }
    float o[16];
#pragma unroll
    for (int oc = 0; oc < 16; oc++) {
        float a = b1[oc];
#pragma unroll
        for (int j = 0; j < 27; j++) a += v[j] * w1[oc * 27 + j];
        o[oc] = a / (1.f + __expf(-a));
    }
    unsigned int u[8];
#pragma unroll
    for (int i = 0; i < 8; i++)
        u[i] = (unsigned int)bfbits(o[2 * i]) | ((unsigned int)bfbits(o[2 * i + 1]) << 16);
    size_t pidx = ((size_t)(h + 1) * HP + (w + 1)) * 8;
    *(uint4*)(h1p + (size_t)(b * 2 + 0) * SZP + pidx) = make_uint4(u[0], u[1], u[2], u[3]);
    *(uint4*)(h1p + (size_t)(b * 2 + 1) * SZP + pidx) = make_uint4(u[4], u[5], u[6], u[7]);
}

// ---------------- conv2 via split-precision MFMA, fused with conv3-mean reduction ----------------
// Wave = 64 px of one row (4 tiles of 16). D[oc][px] = sum_ks (A_hi + A_lo)(16x32) B(32x16).
__global__ __launch_bounds__(256) void conv2_kernel(const __hip_bfloat16* __restrict__ h1p,
                                                    const unsigned short* __restrict__ abuf,
                                                    const float* __restrict__ b2,
                                                    float* __restrict__ wsf) {
    int lane = threadIdx.x & 63;
    int wave = threadIdx.x >> 6;
    int h = blockIdx.y, b = blockIdx.z;
    int w0 = blockIdx.x * 256 + wave * 64;
    int n = lane & 15, q = lane >> 4;

    union { uint4 u; bf16x8 v; } cv;
    bf16x8 ah[5], al[5];
    const uint4* ab4 = (const uint4*)abuf;
#pragma unroll
    for (int ks = 0; ks < 5; ks++) {
        cv.u = ab4[ks * 64 + lane];       ah[ks] = cv.v;
        cv.u = ab4[320 + ks * 64 + lane]; al[ks] = cv.v;   // lo block starts at 2560 bf16 = 320 uint4
    }

    f32x4 acc[4] = {{0,0,0,0},{0,0,0,0},{0,0,0,0},{0,0,0,0}};
#pragma unroll
    for (int ks = 0; ks < 5; ks++) {
        int tap = 2 * ks + (q >> 1); if (tap > 8) tap = 8;   // pad half: A is zero there
        int dh = tap / 3 - 1, dw = tap % 3 - 1;
        int half = q & 1;
        const __hip_bfloat16* base = h1p + (size_t)(b * 2 + half) * SZP
                                   + ((size_t)(h + 1 + dh) * HP + (w0 + 1 + dw + n)) * 8;
#pragma unroll
        for (int t = 0; t < 4; t++) {
            cv.u = *(const uint4*)(base + (size_t)t * 16 * 8);
            acc[t] = __builtin_amdgcn_mfma_f32_16x16x32_bf16(ah[ks], cv.v, acc[t], 0, 0, 0);
            acc[t] = __builtin_amdgcn_mfma_f32_16x16x32_bf16(al[ks], cv.v, acc[t], 0, 0, 0);
        }
    }
    // silu epilogue; lane holds oc = q*4+r at px = w0 + t*16 + n
    float sv[4][4];
#pragma unroll
    for (int t = 0; t < 4; t++)
#pragma unroll
        for (int r = 0; r < 4; r++) {
            float a = acc[t][r] + b2[q * 4 + r];
            sv[t][r] = a / (1.f + __expf(-a));
        }
    float rs[4];
#pragma unroll
    for (int r = 0; r < 4; r++) {
        float x = sv[0][r] + sv[1][r] + sv[2][r] + sv[3][r];
#pragma unroll
        for (int d = 1; d < 16; d <<= 1) x += __shfl_xor(x, d, 64);
        rs[r] = x;                           // 64-px row sum for oc=q*4+r
    }
    __shared__ float part[4][16];
    if (n == 0)
#pragma unroll
        for (int r = 0; r < 4; r++) part[wave][q * 4 + r] = rs[r];
    __syncthreads();
    int tid = threadIdx.x;
    if (tid < 16)
        atomicAdd(&wsf[OFF_TOT + b * 16 + tid],
                  part[0][tid] + part[1][tid] + part[2][tid] + part[3][tid]);
    if ((h == 0 || h == HH - 1) && n == 0) {
        int off = (h == 0) ? OFF_ROW0 : OFF_ROW1;
#pragma unroll
        for (int r = 0; r < 4; r++) atomicAdd(&wsf[off + b * 16 + q * 4 + r], rs[r]);
    }
    bool isc0 = (blockIdx.x == 0 && wave == 0 && n == 0);        // w == 0 (tile 0)
    bool isc1 = (blockIdx.x == 1 && wave == 3 && n == 15);       // w == 511 (tile 3)
    if (isc0)
#pragma unroll
        for (int r = 0; r < 4; r++) atomicAdd(&wsf[OFF_COL0 + b * 16 + q * 4 + r], sv[0][r]);
    if (isc1)
#pragma unroll
        for (int r = 0; r < 4; r++) atomicAdd(&wsf[OFF_COL1 + b * 16 + q * 4 + r], sv[3][r]);
    if ((h == 0 || h == HH - 1) && (isc0 || isc1)) {
        int hi = (h == 0) ? 0 : 1, wi = isc0 ? 0 : 1, t = isc0 ? 0 : 3;
#pragma unroll
        for (int r = 0; r < 4; r++)
            wsf[OFF_COR + ((b * 2 + hi) * 2 + wi) * 16 + q * 4 + r] = sv[t][r];
    }
}

// ---------------- filter: assemble mean via edge algebra, build separable taps ----------------
__global__ void filter_kernel(const float* __restrict__ w3, const float* __restrict__ b3,
                              float* __restrict__ wsf) {
    int b = blockIdx.x, t = threadIdx.x;   // 160 threads
    __shared__ float red[160];
    float val = 0.f;
    if (t < 144) {
        int ic = t / 9, tap = t % 9, kh = tap / 3, kw = tap % 3;
        float T = wsf[OFF_TOT + b * 16 + ic];
        int hi = -1, wi = -1;
        if (kh == 0) { T -= wsf[OFF_ROW1 + b * 16 + ic]; hi = 1; }
        else if (kh == 2) { T -= wsf[OFF_ROW0 + b * 16 + ic]; hi = 0; }
        if (kw == 0) { T -= wsf[OFF_COL1 + b * 16 + ic]; wi = 1; }
        else if (kw == 2) { T -= wsf[OFF_COL0 + b * 16 + ic]; wi = 0; }
        if (hi >= 0 && wi >= 0) T += wsf[OFF_COR + ((b * 2 + hi) * 2 + wi) * 16 + ic];
        val = w3[t] * T;
    }
    red[t] = val;
    __syncthreads();
    __shared__ float sh_mean;
    if (t == 0) {
        float S = 0.f;
        for (int i = 0; i < 144; i++) S += red[i];
        sh_mean = b3[0] + S * (1.f / (float)PIX);
    }
    __syncthreads();
    float scale = fminf(2.5f, fmaxf(-2.5f, sh_mean));
    float sd = exp2f(scale);
    float fs = ceilf(3.f * sd + 0.5f);
    float e = 0.f, c = 0.f;
    if (t < 37) {
        float x = (float)(t - 18);
        if (fabsf(x) <= fs) {
            float qq = x / sd;
            e = __expf(-0.5f * qq * qq);
            c = -x / (sd * sd * sd * 6.28318530717958647692f) * e;
        }
    }
    __shared__ float sa[40], sb[40];
    if (t < 37) { sa[t] = e; sb[t] = fabsf(c); }
    __syncthreads();
    __shared__ float Se, Sc;
    if (t == 0) {
        float a = 0.f, d = 0.f;
        for (int i = 0; i < 37; i++) { a += sa[i]; d += sb[i]; }
        Se = a; Sc = d;
    }
    __syncthreads();
    if (t < 37) {
        wsf[OFF_EH + b * 37 + t] = e / Se;
        wsf[OFF_CH + b * 37 + t] = c / Sc;
    }
}

// ---------------- xg = gcm*batch + RGB_order -> out ch2..4 (4 px/thread) ----------------
__global__ __launch_bounds__(256) void xgrgb_kernel(const float* __restrict__ batch,
                                                    const float* __restrict__ gcm,
                                                    float* __restrict__ xg,
                                                    float* __restrict__ out) {
    int w4 = (blockIdx.x * 64 + threadIdx.x) * 4;
    int h = blockIdx.y * 4 + threadIdx.y;
    int b = blockIdx.z;
    size_t p = (size_t)h * WW + w4;
    float4 v0 = *(const float4*)(batch + (size_t)(b * 3 + 0) * PIX + p);
    float4 v1 = *(const float4*)(batch + (size_t)(b * 3 + 1) * PIX + p);
    float4 v2 = *(const float4*)(batch + (size_t)(b * 3 + 2) * PIX + p);
    float g[9];
#pragma unroll
    for (int i = 0; i < 9; i++) g[i] = gcm[i];
#pragma unroll
    for (int i = 0; i < 3; i++) {
        float4 o;
        o.x = g[i*3] * v0.x + g[i*3+1] * v1.x + g[i*3+2] * v2.x;
        o.y = g[i*3] * v0.y + g[i*3+1] * v1.y + g[i*3+2] * v2.y;
        o.z = g[i*3] * v0.z + g[i*3+1] * v1.z + g[i*3+2] * v2.z;
        o.w = g[i*3] * v0.w + g[i*3+1] * v1.w + g[i*3+2] * v2.w;
        *(float4*)(xg + (size_t)(b * 3 + i) * PIX + p) = o;
    }
    float a0[4] = {v0.x, v0.y, v0.z, v0.w};
    float a1[4] = {v1.x, v1.y, v1.z, v1.w};
    float a2[4] = {v2.x, v2.y, v2.z, v2.w};
    float r[3][4];
#pragma unroll
    for (int j = 0; j < 4; j++) {
        float x0 = a0[j], x1 = a1[j], x2 = a2[j];
        int mx  = (x0 >= x1 && x0 >= x2) ? 0 : ((x1 >= x2) ? 1 : 2);
        int mx2 = (x2 >= x1 && x2 >= x0) ? 2 : ((x1 >= x0) ? 1 : 0);
        int mn  = (x0 <= x1 && x0 <= x2) ? 0 : ((x1 <= x2) ? 1 : 2);
        int mn2 = (x2 <= x1 && x2 <= x0) ? 2 : ((x1 <= x0) ? 1 : 0);
#pragma unroll
        for (int c = 0; c < 3; c++)
            r[c][j] = 0.5f * ((float)(c == mx) + (float)(c == mx2))
                    - 0.5f * ((float)(c == mn) + (float)(c == mn2));
    }
#pragma unroll
    for (int c = 0; c < 3; c++) {
        float4 o = {r[c][0], r[c][1], r[c][2], r[c][3]};
        *(float4*)(out + (size_t)(b * 6 + 2 + c) * PIX + p) = o;
    }
}

// ---------------- horizontal separable pass: xg -> t0..t3 ----------------
__global__ __launch_bounds__(256) void horiz_kernel(const float* __restrict__ xg,
                                                    const float* __restrict__ ehat,
                                                    const float* __restrict__ chat,
                                                    float* __restrict__ t) {
    __shared__ float L[3][296];
    int tid = threadIdx.x;
    int w0 = blockIdx.x * 256;
    int h = blockIdx.y;
    int b = blockIdx.z;
    for (int i = tid; i < 3 * 292; i += 256) {
        int c = i / 292, j = i - c * 292;
        int gw = w0 - 18 + j;
        float x = 0.f;
        if (gw >= 0 && gw < WW) x = xg[(size_t)(b * 3 + c) * PIX + h * WW + gw];
        L[c][j] = x;
    }
    __syncthreads();
    const float* eh = ehat + b * 37; const float* ch = chat + b * 37;
    float s0e = 0.f, s0c = 0.f, s1e = 0.f, s2e = 0.f;
    for (int k = 0; k < 37; k++) {
        float ce = eh[k], cc = ch[k];
        float a0 = L[0][tid + k], a1 = L[1][tid + k], a2 = L[2][tid + k];
        s0e += ce * a0; s0c += cc * a0; s1e += ce * a1; s2e += ce * a2;
    }
    int w = w0 + tid;
    size_t p = (size_t)b * PIX + h * WW + w;
    const size_t PL = (size_t)BN * PIX;
    t[0 * PL + p] = s0e;
    t[1 * PL + p] = s1e;
    t[2 * PL + p] = s2e;
    t[3 * PL + p] = s0c;
}

// ---------------- vertical pass + final math -> out ch0,1,5 (4 rows/thread) ----------------
__global__ __launch_bounds__(256) void vert_kernel(const float* __restrict__ t,
                                                   const float* __restrict__ ehat,
                                                   const float* __restrict__ chat,
                                                   float* __restrict__ out) {
    int tx = threadIdx.x, ty = threadIdx.y;
    int w = blockIdx.x * 64 + tx;
    int b = blockIdx.z;
    int h0 = (blockIdx.y * 4 + ty) * 4;
    const float* eh = ehat + b * 37; const float* ch = chat + b * 37;
    const size_t PL = (size_t)BN * PIX;
    const float* t0 = t + 0 * PL + (size_t)b * PIX;
    const float* t1 = t + 1 * PL + (size_t)b * PIX;
    const float* t2 = t + 2 * PL + (size_t)b * PIX;
    const float* t3 = t + 3 * PL + (size_t)b * PIX;
    float E[4] = {0,0,0,0}, Ex[4] = {0,0,0,0}, Ey[4] = {0,0,0,0};
    float El[4] = {0,0,0,0}, Ell[4] = {0,0,0,0};
    for (int jj = 0; jj < 40; jj++) {
        int j = h0 - 18 + jj;
        if (j < 0 || j >= HH) continue;
        int idx = j * WW + w;
        float a0 = t0[idx], a1 = t1[idx], a2 = t2[idx], a3 = t3[idx];
#pragma unroll
        for (int i = 0; i < 4; i++) {
            int k = jj - i;
            if (k >= 0 && k < 37) {
                float ce = eh[k], cc = ch[k];
                E[i] += ce * a0; Ex[i] += cc * a0; Ey[i] += ce * a3;
                El[i] += ce * a1; Ell[i] += ce * a2;
            }
        }
    }
#pragma unroll
    for (int i = 0; i < 4; i++) {
        int h = h0 + i;
        float Hf = atanf(El[i] / (Ell[i] + EPSF));
        float S = logf((El[i] * El[i] + Ell[i] * Ell[i]) / (E[i] * E[i] + EPSF) + EPSF);
        float rx = Ex[i] / (E[i] + EPSF), ry = Ey[i] / (E[i] + EPSF);
        float Wv = atanf(rx * rx + ry * ry);
        size_t base = (size_t)(b * 6) * PIX + h * WW + w;
        out[base] = Hf;
        out[base + PIX] = S;
        out[base + 5 * (size_t)PIX] = Wv;
    }
}

extern "C" void kernel_launch(void* const* d_in, const int* in_sizes, int n_in,
                              void* d_out, int out_size, void* d_ws, size_t ws_size,
                              hipStream_t stream) {
    const float* batch = (const float*)d_in[0];
    const float* gcm   = (const float*)d_in[1];
    const float* w1    = (const float*)d_in[2];
    const float* b1    = (const float*)d_in[3];
    const float* w2    = (const float*)d_in[4];
    const float* b2    = (const float*)d_in[5];
    const float* w3    = (const float*)d_in[6];
    const float* b3    = (const float*)d_in[7];
    float* out = (float*)d_out;

    if (ws_size < WS_NEEDED) return;

    float* wsf = (float*)d_ws;
    __hip_bfloat16* h1p = (__hip_bfloat16*)((char*)d_ws + OFF_H1B);
    float* xg  = (float*)((char*)d_ws + OFF_XGB);
    float* tpl = (float*)((char*)d_ws + OFF_TPB);
    float* ehat = wsf + OFF_EH;
    float* chat = wsf + OFF_CH;

    prep_kernel<<<dim3(1), dim3(256), 0, stream>>>(w2, wsf);
    border_kernel<<<dim3(16), dim3(256), 0, stream>>>(h1p);

    dim3 blk(64, 4);
    conv1_kernel<<<dim3(8, 128, 8), blk, 0, stream>>>(batch, w1, b1, h1p);
    conv2_kernel<<<dim3(2, 512, 8), dim3(256), 0, stream>>>(
        h1p, (const unsigned short*)(wsf + OFF_WR), b2, wsf);
    filter_kernel<<<dim3(8), dim3(160), 0, stream>>>(w3, b3, wsf);
    xgrgb_kernel<<<dim3(2, 128, 8), blk, 0, stream>>>(batch, gcm, xg, out);
    horiz_kernel<<<dim3(2, 512, 8), dim3(256), 0, stream>>>(xg, ehat, chat, tpl);
    vert_kernel<<<dim3(8, 32, 8), blk, 0, stream>>>(tpl, ehat, chat, out);
}

// Round 6
// 255.327 us; speedup vs baseline: 4.3338x; 1.2187x over previous
//
#include <hip/hip_runtime.h>
#include <hip/hip_bf16.h>

constexpr int BN = 8, HH = 512, WW = 512;
constexpr int PIX = HH * WW;
constexpr float EPSF = 1e-4f;

__device__ __forceinline__ float b2f(__hip_bfloat16 x) { return __bfloat162float(x); }
__device__ __forceinline__ __hip_bfloat16 f2b(float x) { return __float2bfloat16(x); }
__device__ __forceinline__ unsigned short bfbits(float x) {
    union { __hip_bfloat16 b; unsigned short u; } cv; cv.b = f2b(x); return cv.u;
}

typedef __attribute__((ext_vector_type(8))) short bf16x8;   // MFMA A/B frag (4 VGPRs)
typedef __attribute__((ext_vector_type(4))) float f32x4;    // MFMA C/D frag

// ---- workspace float offsets (small region) ----
constexpr int OFF_TOT = 0;       // 8*16 per-image channel totals (atomics)
constexpr int OFF_ROW0 = 128;
constexpr int OFF_ROW1 = 256;
constexpr int OFF_COL0 = 384;
constexpr int OFF_COL1 = 512;
constexpr int OFF_COR = 640;     // corners [b][hi][wi][16]
constexpr int OFF_WR  = 2048;    // A-fragment weights hi(2560 bf16) + lo(2560 bf16)
constexpr int OFF_EH  = 4608;    // 8*37
constexpr int OFF_CH  = 5120;    // 8*37
// ---- big buffers (byte offsets): no h1 in HBM anymore ----
constexpr size_t OFF_XGB = 65536;                          // xg fp32 (3 planes/img)
constexpr size_t XG_BYTES = (size_t)BN * 3 * PIX * 4;      // 25,165,824
constexpr size_t OFF_TPB = OFF_XGB + XG_BYTES;             // tpl fp32 (4 planes)
constexpr size_t TP_BYTES = (size_t)4 * BN * PIX * 4;      // 33,554,432
constexpr size_t WS_NEEDED = OFF_TPB + TP_BYTES;           // 58,785,792 (134 MB proven)

// ---------------- prep: zero atomic slots, swizzle w2 into hi/lo A-fragments ----------------
// A[m=oc][k], k = ks*32 + q*8 + j ; tap = 2ks + (q>>1), ic = (q&1)*8 + j.
// hi = rn-bf16(w), lo = rn-bf16(w - hi): split recovers ~fp32 weight precision (round-4 lesson:
// bf16-only w2 perturbs mean(s) enough to flip the discontinuous ceil() in fs -> pi-flips in Hf).
__global__ void prep_kernel(const float* __restrict__ w2, float* __restrict__ wsf) {
    int t = threadIdx.x;
    for (int i = t; i < 640; i += 256) wsf[i] = 0.f;
    unsigned short* ab = (unsigned short*)(wsf + OFF_WR);
    for (int idx = t; idx < 5120; idx += 256) {
        int part = idx / 2560;               // 0 = hi, 1 = lo
        int id = idx - part * 2560;
        int ks = id >> 9, rem = id & 511, lane = rem >> 3, j = id & 7;
        int oc = lane & 15, q = lane >> 4;
        int k = q * 8 + j;
        int tap = 2 * ks + (k >> 4), ic = k & 15;
        float val = (tap <= 8) ? w2[oc * 144 + ic * 9 + tap] : 0.f;
        float hv = b2f(f2b(val));
        ab[idx] = (part == 0) ? bfbits(val) : bfbits(val - hv);
    }
}

// ---------------- fused conv1+conv2(+xg+RGB) with conv3-mean reduction ----------------
// Block = 64 px x 16 rows. Phase 1: conv1 -> h1 window (66x18, bf16) in LDS (halo zero-padded,
// identical bf16 rounding as the old h1-in-HBM path). Phase 1b: xg + RGB for the center region.
// Phase 2: per wave 4 rows, B-frags via ds_read_b128 (16B-chunk swizzle -> 2-way = free),
// split-precision MFMA, silu, edge-algebra reductions for the conv3 mean.
__global__ __launch_bounds__(256) void conv12_kernel(const float* __restrict__ batch,
                                                     const float* __restrict__ w1,
                                                     const float* __restrict__ b1,
                                                     const unsigned short* __restrict__ abuf,
                                                     const float* __restrict__ b2v,
                                                     const float* __restrict__ gcm,
                                                     float* __restrict__ wsf,
                                                     float* __restrict__ xg,
                                                     float* __restrict__ out) {
    __shared__ uint4 h1s[18 * 66 * 2];     // [(r*66+c)*2 + (half ^ ((c>>2)&1))], 38,016 B
    __shared__ float part[4][16];

    int tx = threadIdx.x;
    int lane = tx & 63, wave = tx >> 6;
    int n = lane & 15, q = lane >> 4;
    int w0 = blockIdx.x * 64, h0 = blockIdx.y * 16, b = blockIdx.z;

    // A-fragments (tiny, L2-hot) — issue before LDS work to overlap
    union { uint4 u; bf16x8 v; } cv;
    bf16x8 ah[5], al[5];
    const uint4* ab4 = (const uint4*)abuf;
#pragma unroll
    for (int ks = 0; ks < 5; ks++) {
        cv.u = ab4[ks * 64 + lane];       ah[ks] = cv.v;
        cv.u = ab4[320 + ks * 64 + lane]; al[ks] = cv.v;
    }

    // ---- phase 1: conv1 into LDS (66x18 window incl. 1-px halo) ----
    const float* pb = batch + (size_t)(b * 3) * PIX;
    for (int i = tx; i < 18 * 66; i += 256) {
        int r = i / 66, c = i - r * 66;
        int gh = h0 - 1 + r, gw = w0 - 1 + c;
        unsigned int u[8];
        if (gh >= 0 && gh < HH && gw >= 0 && gw < WW) {
            float v[27];
#pragma unroll
            for (int ic = 0; ic < 3; ic++) {
                const float* p = pb + (size_t)ic * PIX;
#pragma unroll
                for (int kh = 0; kh < 3; kh++) {
                    int hh = gh + kh - 1;
#pragma unroll
                    for (int kw = 0; kw < 3; kw++) {
                        int ww = gw + kw - 1;
                        float x = 0.f;
                        if (hh >= 0 && hh < HH && ww >= 0 && ww < WW) x = p[hh * WW + ww];
                        v[ic * 9 + kh * 3 + kw] = x;
                    }
                }
            }
            float o[16];
#pragma unroll
            for (int oc = 0; oc < 16; oc++) {
                float a = b1[oc];
#pragma unroll
                for (int j = 0; j < 27; j++) a += v[j] * w1[oc * 27 + j];
                o[oc] = a / (1.f + __expf(-a));
            }
#pragma unroll
            for (int k = 0; k < 8; k++)
                u[k] = (unsigned int)bfbits(o[2 * k]) | ((unsigned int)bfbits(o[2 * k + 1]) << 16);
        } else {
#pragma unroll
            for (int k = 0; k < 8; k++) u[k] = 0u;
        }
        int swz = (c >> 2) & 1;
        int base = i * 2;
        h1s[base + swz]       = make_uint4(u[0], u[1], u[2], u[3]);   // logical half 0
        h1s[base + (swz ^ 1)] = make_uint4(u[4], u[5], u[6], u[7]);   // logical half 1
    }

    // ---- phase 1b: xg + RGB_order for the 64x16 center region ----
    for (int j = tx; j < 1024; j += 256) {
        int rr = j >> 6, ccx = j & 63;
        int gh = h0 + rr, gw = w0 + ccx;
        size_t p = (size_t)gh * WW + gw;
        float v0 = pb[p], v1 = pb[(size_t)PIX + p], v2 = pb[2 * (size_t)PIX + p];
#pragma unroll
        for (int i = 0; i < 3; i++)
            xg[(size_t)(b * 3 + i) * PIX + p] =
                gcm[i * 3] * v0 + gcm[i * 3 + 1] * v1 + gcm[i * 3 + 2] * v2;
        int mx  = (v0 >= v1 && v0 >= v2) ? 0 : ((v1 >= v2) ? 1 : 2);
        int mx2 = (v2 >= v1 && v2 >= v0) ? 2 : ((v1 >= v0) ? 1 : 0);
        int mn  = (v0 <= v1 && v0 <= v2) ? 0 : ((v1 <= v2) ? 1 : 2);
        int mn2 = (v2 <= v1 && v2 <= v0) ? 2 : ((v1 <= v0) ? 1 : 0);
#pragma unroll
        for (int c = 0; c < 3; c++) {
            float r = 0.5f * ((float)(c == mx) + (float)(c == mx2))
                    - 0.5f * ((float)(c == mn) + (float)(c == mn2));
            out[(size_t)(b * 6 + 2 + c) * PIX + p] = r;
        }
    }
    __syncthreads();

    // ---- phase 2: conv2 MFMA from LDS; wave handles rows wave*4..wave*4+3 ----
    float tt[4] = {0, 0, 0, 0};          // running totals per oc=q*4+reg
    float cs0[4] = {0, 0, 0, 0};         // col-0 sums (lane n==0, tile 0, blockIdx.x==0)
    float cs1[4] = {0, 0, 0, 0};         // col-511 sums (lane n==15, tile 3, blockIdx.x==7)
    for (int rloc = 0; rloc < 4; rloc++) {
        int row = wave * 4 + rloc;       // local output row 0..15
        int grow = h0 + row;
        f32x4 acc[4] = {{0,0,0,0},{0,0,0,0},{0,0,0,0},{0,0,0,0}};
#pragma unroll
        for (int ks = 0; ks < 5; ks++) {
            int tap = 2 * ks + (q >> 1); if (tap > 8) tap = 8;   // pad slice: A is zero there
            int dh = tap / 3 - 1, dw = tap % 3 - 1;
            int half = q & 1;
            int lr = row + 1 + dh;
#pragma unroll
            for (int t = 0; t < 4; t++) {
                int c = 1 + dw + t * 16 + n;
                cv.u = h1s[(lr * 66 + c) * 2 + (half ^ ((c >> 2) & 1))];
                acc[t] = __builtin_amdgcn_mfma_f32_16x16x32_bf16(ah[ks], cv.v, acc[t], 0, 0, 0);
                acc[t] = __builtin_amdgcn_mfma_f32_16x16x32_bf16(al[ks], cv.v, acc[t], 0, 0, 0);
            }
        }
        float sv[4][4];
#pragma unroll
        for (int t = 0; t < 4; t++)
#pragma unroll
            for (int r = 0; r < 4; r++) {
                float a = acc[t][r] + b2v[q * 4 + r];
                sv[t][r] = a / (1.f + __expf(-a));
            }
#pragma unroll
        for (int r = 0; r < 4; r++) tt[r] += sv[0][r] + sv[1][r] + sv[2][r] + sv[3][r];
        if (grow == 0 || grow == HH - 1) {
            int off = (grow == 0) ? OFF_ROW0 : OFF_ROW1;
#pragma unroll
            for (int r = 0; r < 4; r++) {
                float x = sv[0][r] + sv[1][r] + sv[2][r] + sv[3][r];
#pragma unroll
                for (int d = 1; d < 16; d <<= 1) x += __shfl_xor(x, d, 64);
                if (n == 0) atomicAdd(&wsf[off + b * 16 + q * 4 + r], x);
            }
        }
        if (blockIdx.x == 0 && n == 0)
#pragma unroll
            for (int r = 0; r < 4; r++) cs0[r] += sv[0][r];
        if (blockIdx.x == 7 && n == 15)
#pragma unroll
            for (int r = 0; r < 4; r++) cs1[r] += sv[3][r];
        if ((grow == 0 || grow == HH - 1)) {
            int hi = (grow == 0) ? 0 : 1;
            if (blockIdx.x == 0 && n == 0)
#pragma unroll
                for (int r = 0; r < 4; r++)
                    wsf[OFF_COR + ((b * 2 + hi) * 2 + 0) * 16 + q * 4 + r] = sv[0][r];
            if (blockIdx.x == 7 && n == 15)
#pragma unroll
                for (int r = 0; r < 4; r++)
                    wsf[OFF_COR + ((b * 2 + hi) * 2 + 1) * 16 + q * 4 + r] = sv[3][r];
        }
    }
    if (blockIdx.x == 0 && n == 0)
#pragma unroll
        for (int r = 0; r < 4; r++) atomicAdd(&wsf[OFF_COL0 + b * 16 + q * 4 + r], cs0[r]);
    if (blockIdx.x == 7 && n == 15)
#pragma unroll
        for (int r = 0; r < 4; r++) atomicAdd(&wsf[OFF_COL1 + b * 16 + q * 4 + r], cs1[r]);
#pragma unroll
    for (int r = 0; r < 4; r++) {
        float x = tt[r];
#pragma unroll
        for (int d = 1; d < 16; d <<= 1) x += __shfl_xor(x, d, 64);
        tt[r] = x;
    }
    if (n == 0)
#pragma unroll
        for (int r = 0; r < 4; r++) part[wave][q * 4 + r] = tt[r];
    __syncthreads();
    if (tx < 16)
        atomicAdd(&wsf[OFF_TOT + b * 16 + tx],
                  part[0][tx] + part[1][tx] + part[2][tx] + part[3][tx]);
}

// ---------------- filter: assemble mean via edge algebra, build separable taps ----------------
__global__ void filter_kernel(const float* __restrict__ w3, const float* __restrict__ b3,
                              float* __restrict__ wsf) {
    int b = blockIdx.x, t = threadIdx.x;   // 160 threads
    __shared__ float red[160];
    float val = 0.f;
    if (t < 144) {
        int ic = t / 9, tap = t % 9, kh = tap / 3, kw = tap % 3;
        float T = wsf[OFF_TOT + b * 16 + ic];
        int hi = -1, wi = -1;
        if (kh == 0) { T -= wsf[OFF_ROW1 + b * 16 + ic]; hi = 1; }
        else if (kh == 2) { T -= wsf[OFF_ROW0 + b * 16 + ic]; hi = 0; }
        if (kw == 0) { T -= wsf[OFF_COL1 + b * 16 + ic]; wi = 1; }
        else if (kw == 2) { T -= wsf[OFF_COL0 + b * 16 + ic]; wi = 0; }
        if (hi >= 0 && wi >= 0) T += wsf[OFF_COR + ((b * 2 + hi) * 2 + wi) * 16 + ic];
        val = w3[t] * T;
    }
    red[t] = val;
    __syncthreads();
    __shared__ float sh_mean;
    if (t == 0) {
        float S = 0.f;
        for (int i = 0; i < 144; i++) S += red[i];
        sh_mean = b3[0] + S * (1.f / (float)PIX);
    }
    __syncthreads();
    float scale = fminf(2.5f, fmaxf(-2.5f, sh_mean));
    float sd = exp2f(scale);
    float fs = ceilf(3.f * sd + 0.5f);
    float e = 0.f, c = 0.f;
    if (t < 37) {
        float x = (float)(t - 18);
        if (fabsf(x) <= fs) {
            float qq = x / sd;
            e = __expf(-0.5f * qq * qq);
            c = -x / (sd * sd * sd * 6.28318530717958647692f) * e;
        }
    }
    __shared__ float sa[40], sb[40];
    if (t < 37) { sa[t] = e; sb[t] = fabsf(c); }
    __syncthreads();
    __shared__ float Se, Sc;
    if (t == 0) {
        float a = 0.f, d = 0.f;
        for (int i = 0; i < 37; i++) { a += sa[i]; d += sb[i]; }
        Se = a; Sc = d;
    }
    __syncthreads();
    if (t < 37) {
        wsf[OFF_EH + b * 37 + t] = e / Se;
        wsf[OFF_CH + b * 37 + t] = c / Sc;
    }
}

// ---------------- horizontal separable pass: xg -> t0..t3 ----------------
__global__ __launch_bounds__(256) void horiz_kernel(const float* __restrict__ xg,
                                                    const float* __restrict__ ehat,
                                                    const float* __restrict__ chat,
                                                    float* __restrict__ t) {
    __shared__ float L[3][296];
    int tid = threadIdx.x;
    int w0 = blockIdx.x * 256;
    int h = blockIdx.y;
    int b = blockIdx.z;
    for (int i = tid; i < 3 * 292; i += 256) {
        int c = i / 292, j = i - c * 292;
        int gw = w0 - 18 + j;
        float x = 0.f;
        if (gw >= 0 && gw < WW) x = xg[(size_t)(b * 3 + c) * PIX + h * WW + gw];
        L[c][j] = x;
    }
    __syncthreads();
    const float* eh = ehat + b * 37; const float* ch = chat + b * 37;
    float s0e = 0.f, s0c = 0.f, s1e = 0.f, s2e = 0.f;
    for (int k = 0; k < 37; k++) {
        float ce = eh[k], cc = ch[k];
        float a0 = L[0][tid + k], a1 = L[1][tid + k], a2 = L[2][tid + k];
        s0e += ce * a0; s0c += cc * a0; s1e += ce * a1; s2e += ce * a2;
    }
    int w = w0 + tid;
    size_t p = (size_t)b * PIX + h * WW + w;
    const size_t PL = (size_t)BN * PIX;
    t[0 * PL + p] = s0e;
    t[1 * PL + p] = s1e;
    t[2 * PL + p] = s2e;
    t[3 * PL + p] = s0c;
}

// ---------------- vertical pass + final math -> out ch0,1,5 (4 rows x 4 px/thread) ----------------
__global__ __launch_bounds__(256) void vert_kernel(const float* __restrict__ t,
                                                   const float* __restrict__ ehat,
                                                   const float* __restrict__ chat,
                                                   float* __restrict__ out) {
    int tx = threadIdx.x, ty = threadIdx.y;
    int w4 = (blockIdx.x * 64 + tx) * 4;
    int b = blockIdx.z;
    int h0 = (blockIdx.y * 4 + ty) * 4;
    const float* eh = ehat + b * 37; const float* ch = chat + b * 37;
    const size_t PL = (size_t)BN * PIX;
    const float* t0 = t + 0 * PL + (size_t)b * PIX;
    const float* t1 = t + 1 * PL + (size_t)b * PIX;
    const float* t2 = t + 2 * PL + (size_t)b * PIX;
    const float* t3 = t + 3 * PL + (size_t)b * PIX;
    float E[4][4] = {}, Ex[4][4] = {}, Ey[4][4] = {}, El[4][4] = {}, Ell[4][4] = {};
    for (int jj = 0; jj < 40; jj++) {
        int j = h0 - 18 + jj;
        if (j < 0 || j >= HH) continue;
        size_t idx = (size_t)j * WW + w4;
        float4 a0 = *(const float4*)(t0 + idx);
        float4 a1 = *(const float4*)(t1 + idx);
        float4 a2 = *(const float4*)(t2 + idx);
        float4 a3 = *(const float4*)(t3 + idx);
        float c0[4] = {a0.x, a0.y, a0.z, a0.w};
        float c1[4] = {a1.x, a1.y, a1.z, a1.w};
        float c2[4] = {a2.x, a2.y, a2.z, a2.w};
        float c3[4] = {a3.x, a3.y, a3.z, a3.w};
#pragma unroll
        for (int i = 0; i < 4; i++) {
            int k = jj - i;
            if (k >= 0 && k < 37) {
                float ce = eh[k], cc = ch[k];
#pragma unroll
                for (int x = 0; x < 4; x++) {
                    E[i][x] += ce * c0[x]; Ex[i][x] += cc * c0[x]; Ey[i][x] += ce * c3[x];
                    El[i][x] += ce * c1[x]; Ell[i][x] += ce * c2[x];
                }
            }
        }
    }
#pragma unroll
    for (int i = 0; i < 4; i++) {
        int h = h0 + i;
        float4 oH, oS, oW;
        float* pH = (float*)&oH; float* pS = (float*)&oS; float* pW = (float*)&oW;
#pragma unroll
        for (int x = 0; x < 4; x++) {
            pH[x] = atanf(El[i][x] / (Ell[i][x] + EPSF));
            pS[x] = logf((El[i][x] * El[i][x] + Ell[i][x] * Ell[i][x])
                         / (E[i][x] * E[i][x] + EPSF) + EPSF);
            float rx = Ex[i][x] / (E[i][x] + EPSF), ry = Ey[i][x] / (E[i][x] + EPSF);
            pW[x] = atanf(rx * rx + ry * ry);
        }
        size_t base = (size_t)(b * 6) * PIX + (size_t)h * WW + w4;
        *(float4*)(out + base) = oH;
        *(float4*)(out + base + PIX) = oS;
        *(float4*)(out + base + 5 * (size_t)PIX) = oW;
    }
}

extern "C" void kernel_launch(void* const* d_in, const int* in_sizes, int n_in,
                              void* d_out, int out_size, void* d_ws, size_t ws_size,
                              hipStream_t stream) {
    const float* batch = (const float*)d_in[0];
    const float* gcm   = (const float*)d_in[1];
    const float* w1    = (const float*)d_in[2];
    const float* b1    = (const float*)d_in[3];
    const float* w2    = (const float*)d_in[4];
    const float* b2    = (const float*)d_in[5];
    const float* w3    = (const float*)d_in[6];
    const float* b3    = (const float*)d_in[7];
    float* out = (float*)d_out;

    if (ws_size < WS_NEEDED) return;

    float* wsf = (float*)d_ws;
    float* xg  = (float*)((char*)d_ws + OFF_XGB);
    float* tpl = (float*)((char*)d_ws + OFF_TPB);
    float* ehat = wsf + OFF_EH;
    float* chat = wsf + OFF_CH;

    prep_kernel<<<dim3(1), dim3(256), 0, stream>>>(w2, wsf);
    conv12_kernel<<<dim3(8, 32, 8), dim3(256), 0, stream>>>(
        batch, w1, b1, (const unsigned short*)(wsf + OFF_WR), b2, gcm, wsf, xg, out);
    filter_kernel<<<dim3(8), dim3(160), 0, stream>>>(w3, b3, wsf);
    horiz_kernel<<<dim3(2, 512, 8), dim3(256), 0, stream>>>(xg, ehat, chat, tpl);
    vert_kernel<<<dim3(2, 32, 8), dim3(64, 4), 0, stream>>>(tpl, ehat, chat, out);
}